// Round 2
// baseline (3293.996 us; speedup 1.0000x reference)
//
#include <hip/hip_runtime.h>

#define TSTEPS 32
#define BSZ    512
#define DIN    1024
#define HID    2048
#define NCLS   10
#define BETA   0.95f
#define VTH    1.0f
#define SPKB   ((size_t)BSZ * (HID / 8))   // 131072 B: one parity buffer of packed spikes

typedef __attribute__((ext_vector_type(4))) float          f4;
typedef __attribute__((ext_vector_type(4))) float          f32x4;
typedef __attribute__((ext_vector_type(8))) __bf16         bf16x8;
typedef __attribute__((ext_vector_type(8))) unsigned short us8;
typedef __attribute__((ext_vector_type(4))) unsigned short us4;

__device__ inline unsigned short f2bf(float f) {
    unsigned u = __float_as_uint(f);
    u += 0x7FFF + ((u >> 16) & 1);          // RNE
    return (unsigned short)(u >> 16);
}
__device__ inline float bf2f(unsigned short h) {
    return __uint_as_float(((unsigned)h) << 16);
}

// split e (8 floats in two f4) into 3 exact bf16 planes
__device__ __forceinline__ void split_f4pair(f4 v0, f4 v1, us8& o0, us8& o1, us8& o2) {
#pragma unroll
    for (int jj = 0; jj < 4; jj++) {
        float v = v0[jj];
        unsigned short h1 = f2bf(v); float r = v - bf2f(h1);
        unsigned short h2 = f2bf(r); float r2 = r - bf2f(h2);
        o0[jj] = h1; o1[jj] = h2; o2[jj] = f2bf(r2);
        v = v1[jj];
        h1 = f2bf(v); r = v - bf2f(h1);
        h2 = f2bf(r); r2 = r - bf2f(h2);
        o0[jj + 4] = h1; o1[jj + 4] = h2; o2[jj + 4] = f2bf(r2);
    }
}

// ---------------------------------------------------------------------------
__global__ __launch_bounds__(256)
void split3(const float* __restrict__ w, const float* __restrict__ m,
            unsigned short* __restrict__ h1, unsigned short* __restrict__ h2,
            unsigned short* __restrict__ h3, int n4)
{
    int i      = blockIdx.x * blockDim.x + threadIdx.x;
    int stride = gridDim.x * blockDim.x;
    for (; i < n4; i += stride) {
        f4 wv = ((const f4*)w)[i];
        f4 mv = ((const f4*)m)[i];
        us4 a, b, c;
#pragma unroll
        for (int j = 0; j < 4; j++) {
            float e  = wv[j] * mv[j];
            unsigned short x1 = f2bf(e);
            float r  = e - bf2f(x1);
            unsigned short x2 = f2bf(r);
            float r2 = r - bf2f(x2);
            a[j] = x1; b[j] = x2; c[j] = f2bf(r2);
        }
        ((us4*)h1)[i] = a;
        ((us4*)h2)[i] = b;
        ((us4*)h3)[i] = c;
    }
}

__global__ __launch_bounds__(256)
void zerof(float* __restrict__ p, int n4)
{
    int i      = blockIdx.x * blockDim.x + threadIdx.x;
    int stride = gridDim.x * blockDim.x;
    f4 z = {0.f, 0.f, 0.f, 0.f};
    for (; i < n4; i += stride) ((f4*)p)[i] = z;
}

// split x_t (no mask) into 3 bf16 planes (plane stride BSZ*DIN ushorts)
__device__ __forceinline__ void xsplit_dev(const float* __restrict__ xt,
                                           unsigned short* __restrict__ dst,
                                           int bid, int nblk, int tid)
{
    const int n4 = BSZ * DIN / 4;              // 131072
    const int PS = BSZ * DIN;
    int i      = bid * 256 + tid;
    int stride = nblk * 256;
    for (; i < n4; i += stride) {
        f4 v = ((const f4*)xt)[i];
        us4 a, b, c;
#pragma unroll
        for (int j = 0; j < 4; j++) {
            float e = v[j];
            unsigned short x1 = f2bf(e);
            float r  = e - bf2f(x1);
            unsigned short x2 = f2bf(r);
            float r2 = r - bf2f(x2);
            a[j] = x1; b[j] = x2; c[j] = f2bf(r2);
        }
        ((us4*)(dst))[i]          = a;
        ((us4*)(dst + PS))[i]     = b;
        ((us4*)(dst + 2 * PS))[i] = c;
    }
}

__global__ __launch_bounds__(256)
void xsplit_k(const float* __restrict__ xt, unsigned short* __restrict__ dst)
{
    xsplit_dev(xt, dst, blockIdx.x, gridDim.x, threadIdx.x);
}

// ---------------------------------------------------------------------------
// shared LIF epilogue (v1/v2): mem RMW + ballot-packed spike bits
// C/D mapping (verified m89/m91): col = lane&15, row = (lane>>4)*4 + reg
// ---------------------------------------------------------------------------
__device__ __forceinline__ void lif_epi(const f32x4 acc[2][2], const float* __restrict__ bias,
                                        float* __restrict__ memOut, unsigned char* __restrict__ sbits,
                                        int bm, int bn, int wm, int wn, int lane)
{
    const int fr = lane & 15;
#pragma unroll
    for (int fm = 0; fm < 2; fm++)
#pragma unroll
        for (int fn = 0; fn < 2; fn++) {
            const int n  = bn * 64 + wn * 32 + fn * 16 + fr;
            const float bv = bias[n];
            const int rbase = bm * 64 + wm * 32 + fm * 16 + (lane >> 4) * 4;
#pragma unroll
            for (int r = 0; r < 4; r++) {
                const int row = rbase + r;
                float* mp = memOut + (size_t)row * HID + n;
                float mo  = *mp;
                float m2  = BETA * mo + (acc[fm][fn][r] + bv) - ((mo > VTH) ? VTH : 0.f);
                *mp = m2;
                unsigned long long bal = __ballot(m2 > VTH);
                if (fr == 0) {  // lanes 0,16,32,48: each writes its own row's 16 col-bits
                    unsigned short bits = (unsigned short)(bal >> ((lane >> 4) * 16));
                    *(unsigned short*)(sbits + (size_t)row * (HID / 8) + bn * 8 + wn * 4 + fn * 2) = bits;
                }
            }
        }
}

// v3 epilogue for 32x32 wave tile, bf16 spike output (per-lane 2B store)
__device__ __forceinline__ void lif_epi_bf(const f32x4 acc[2][2], const float* __restrict__ bias,
                                           float* __restrict__ memOut, unsigned short* __restrict__ spkOut,
                                           int bm, int bn, int wm, int wn, int lane)
{
    const int fr = lane & 15;
#pragma unroll
    for (int fm = 0; fm < 2; fm++)
#pragma unroll
        for (int fn = 0; fn < 2; fn++) {
            const int n  = bn * 64 + wn * 32 + fn * 16 + fr;
            const float bv = bias[n];
            const int rbase = bm * 64 + wm * 32 + fm * 16 + (lane >> 4) * 4;
#pragma unroll
            for (int r = 0; r < 4; r++) {
                const int row = rbase + r;
                float* mp = memOut + (size_t)row * HID + n;
                float mo  = *mp;
                float m2  = BETA * mo + (acc[fm][fn][r] + bv) - ((mo > VTH) ? VTH : 0.f);
                *mp = m2;
                spkOut[(size_t)row * HID + n] = (m2 > VTH) ? (unsigned short)0x3F80
                                                           : (unsigned short)0;
            }
        }
}

// v3 epilogue for 64x16 wave tile (acc[fm], fm=0..3; wave wv owns 16 cols).
// spkOut != null -> bf16 spikes; else ballot bitmap into sbitsOut.
__device__ __forceinline__ void lif_epi4(const f32x4 (&acc)[4], const float* __restrict__ bias,
                                         float* __restrict__ memOut,
                                         unsigned char* __restrict__ sbitsOut,
                                         unsigned short* __restrict__ spkOut,
                                         int bm, int bn, int wv, int lane)
{
    const int fr = lane & 15;
    const int n  = bn * 64 + wv * 16 + fr;
    const float bv = bias[n];
#pragma unroll
    for (int fm = 0; fm < 4; fm++) {
        const int rbase = bm * 64 + fm * 16 + (lane >> 4) * 4;
#pragma unroll
        for (int r = 0; r < 4; r++) {
            const int row = rbase + r;
            float* mp = memOut + (size_t)row * HID + n;
            float mo  = *mp;
            float m2  = BETA * mo + (acc[fm][r] + bv) - ((mo > VTH) ? VTH : 0.f);
            *mp = m2;
            if (spkOut) {
                spkOut[(size_t)row * HID + n] = (m2 > VTH) ? (unsigned short)0x3F80
                                                           : (unsigned short)0;
            } else {
                unsigned long long bal = __ballot(m2 > VTH);
                if (fr == 0) {
                    unsigned short bits = (unsigned short)(bal >> ((lane >> 4) * 16));
                    *(unsigned short*)(sbitsOut + (size_t)row * (HID / 8) + bn * 8 + wv * 2) = bits;
                }
            }
        }
    }
}

// ===========================================================================
// ======================  V1 (fallback) ROLE CODE  ==========================
// ===========================================================================
template<bool ISPLIT>
__device__ __forceinline__ void role_l23(unsigned char* smem,
    const unsigned char* __restrict__ sbitsIn,
    const unsigned short* __restrict__ H1, const unsigned short* __restrict__ H2,
    const unsigned short* __restrict__ H3,
    const float* __restrict__ Wf, const float* __restrict__ Mf,
    const float* __restrict__ bias, float* __restrict__ memOut,
    unsigned char* __restrict__ sbitsOut, int rb, int tid)
{
    auto As = reinterpret_cast<unsigned short(*)[64 * 40]>(smem);              // [2]
    auto Bs = reinterpret_cast<unsigned short(*)[3][64 * 40]>(smem + 10240);   // [2][3]

    const int bn = rb & 31, bm = rb >> 5;
    const int srow = tid >> 2, skq = tid & 3;
    const int lane = tid & 63, wv = tid >> 6;
    const int wm = wv >> 1, wn = wv & 1;
    const int fr = lane & 15, fk = (lane >> 4) * 8;
    const size_t aRowB = (size_t)(bm * 64 + srow) * (HID / 8);
    const size_t bRow  = (size_t)(bn * 64 + srow) * HID;
    const int sdst = srow * 40 + skq * 8;

    f32x4 acc[2][2] = {};

    unsigned char aby = 0;
    us8 bb0, bb1, bb2;
    f4 wv0, wv1, mv0, mv1;

    auto ldnext = [&](int k0) {
        aby = sbitsIn[aRowB + (k0 >> 3) + skq];
        if (ISPLIT) {
            wv0 = *(const f4*)(Wf + bRow + k0 + skq * 8);
            wv1 = *(const f4*)(Wf + bRow + k0 + skq * 8 + 4);
            mv0 = *(const f4*)(Mf + bRow + k0 + skq * 8);
            mv1 = *(const f4*)(Mf + bRow + k0 + skq * 8 + 4);
        } else {
            bb0 = *(const us8*)(H1 + bRow + k0 + skq * 8);
            bb1 = *(const us8*)(H2 + bRow + k0 + skq * 8);
            bb2 = *(const us8*)(H3 + bRow + k0 + skq * 8);
        }
    };
    auto stage = [&](int nb) {
        us8 sa;
#pragma unroll
        for (int jj = 0; jj < 8; jj++)
            sa[jj] = ((aby >> jj) & 1) ? (unsigned short)0x3F80 : (unsigned short)0;
        *(us8*)&As[nb][sdst] = sa;
        if (ISPLIT) {
            us8 q0, q1, q2;
            split_f4pair(wv0 * mv0, wv1 * mv1, q0, q1, q2);
            *(us8*)&Bs[nb][0][sdst] = q0;
            *(us8*)&Bs[nb][1][sdst] = q1;
            *(us8*)&Bs[nb][2][sdst] = q2;
        } else {
            *(us8*)&Bs[nb][0][sdst] = bb0;
            *(us8*)&Bs[nb][1][sdst] = bb1;
            *(us8*)&Bs[nb][2][sdst] = bb2;
        }
    };

    ldnext(0); stage(0);
    __syncthreads();

    const int nsteps = HID / 32;      // 64
    for (int s = 0; s < nsteps; s++) {
        const int buf = s & 1;
        const bool more = (s + 1 < nsteps);
        if (more) ldnext((s + 1) * 32);

        bf16x8 af[2], bf[3][2];
#pragma unroll
        for (int fm = 0; fm < 2; fm++)
            af[fm] = *(const bf16x8*)&As[buf][(wm * 32 + fm * 16 + fr) * 40 + fk];
#pragma unroll
        for (int fn = 0; fn < 2; fn++) {
            bf[0][fn] = *(const bf16x8*)&Bs[buf][0][(wn * 32 + fn * 16 + fr) * 40 + fk];
            bf[1][fn] = *(const bf16x8*)&Bs[buf][1][(wn * 32 + fn * 16 + fr) * 40 + fk];
            bf[2][fn] = *(const bf16x8*)&Bs[buf][2][(wn * 32 + fn * 16 + fr) * 40 + fk];
        }
#pragma unroll
        for (int fm = 0; fm < 2; fm++)
#pragma unroll
            for (int fn = 0; fn < 2; fn++) {
                acc[fm][fn] = __builtin_amdgcn_mfma_f32_16x16x32_bf16(af[fm], bf[0][fn], acc[fm][fn], 0, 0, 0);
                acc[fm][fn] = __builtin_amdgcn_mfma_f32_16x16x32_bf16(af[fm], bf[1][fn], acc[fm][fn], 0, 0, 0);
                acc[fm][fn] = __builtin_amdgcn_mfma_f32_16x16x32_bf16(af[fm], bf[2][fn], acc[fm][fn], 0, 0, 0);
            }

        if (more) stage(buf ^ 1);
        __syncthreads();
    }

    lif_epi(acc, bias, memOut, sbitsOut, bm, bn, wm, wn, lane);
}

__device__ __forceinline__ void role_l1(unsigned char* smem,
    const float* __restrict__ xt, const float* __restrict__ w1,
    const float* __restrict__ m1, const float* __restrict__ bias,
    float* __restrict__ memOut, unsigned char* __restrict__ sbitsOut, int rb, int tid)
{
    auto As = reinterpret_cast<unsigned short(*)[64 * 40]>(smem);              // [3] single-buffered
    auto Bs = reinterpret_cast<unsigned short(*)[3][64 * 40]>(smem + 15360);   // [2][3]

    const int bn = rb & 31, bm = rb >> 5;
    const int srow = tid >> 2, skq = tid & 3;
    const int lane = tid & 63, wv = tid >> 6;
    const int wm = wv >> 1, wn = wv & 1;
    const int fr = lane & 15, fk = (lane >> 4) * 8;
    const size_t aRow = (size_t)(bm * 64 + srow) * DIN;
    const size_t bRow = (size_t)(bn * 64 + srow) * DIN;
    const int sdst = srow * 40 + skq * 8;

    f32x4 acc[2][2] = {};
    f4 xa0, xa1, wv0, wv1, mv0, mv1;

    auto ldnext = [&](int k0) {
        xa0 = *(const f4*)(xt + aRow + k0 + skq * 8);
        xa1 = *(const f4*)(xt + aRow + k0 + skq * 8 + 4);
        wv0 = *(const f4*)(w1 + bRow + k0 + skq * 8);
        wv1 = *(const f4*)(w1 + bRow + k0 + skq * 8 + 4);
        mv0 = *(const f4*)(m1 + bRow + k0 + skq * 8);
        mv1 = *(const f4*)(m1 + bRow + k0 + skq * 8 + 4);
    };
    auto stageA = [&]() {
        us8 p0, p1, p2;
        split_f4pair(xa0, xa1, p0, p1, p2);
        *(us8*)&As[0][sdst] = p0;
        *(us8*)&As[1][sdst] = p1;
        *(us8*)&As[2][sdst] = p2;
    };
    auto stageB = [&](int nb) {
        us8 q0, q1, q2;
        split_f4pair(wv0 * mv0, wv1 * mv1, q0, q1, q2);
        *(us8*)&Bs[nb][0][sdst] = q0;
        *(us8*)&Bs[nb][1][sdst] = q1;
        *(us8*)&Bs[nb][2][sdst] = q2;
    };

    ldnext(0); stageA(); stageB(0);
    __syncthreads();

    const int nsteps = DIN / 32;      // 32
    for (int s = 0; s < nsteps; s++) {
        const bool more = (s + 1 < nsteps);
        if (more) ldnext((s + 1) * 32);

        bf16x8 af[3][2], bf[3][2];
#pragma unroll
        for (int p = 0; p < 3; p++)
#pragma unroll
            for (int f = 0; f < 2; f++) {
                af[p][f] = *(const bf16x8*)&As[p][(wm * 32 + f * 16 + fr) * 40 + fk];
                bf[p][f] = *(const bf16x8*)&Bs[s & 1][p][(wn * 32 + f * 16 + fr) * 40 + fk];
            }
#pragma unroll
        for (int pa = 0; pa < 3; pa++)
#pragma unroll
            for (int pb = 0; pb < 3; pb++) {
                if (pa + pb <= 2) {
#pragma unroll
                    for (int fm = 0; fm < 2; fm++)
#pragma unroll
                        for (int fn = 0; fn < 2; fn++)
                            acc[fm][fn] = __builtin_amdgcn_mfma_f32_16x16x32_bf16(
                                af[pa][fm], bf[pb][fn], acc[fm][fn], 0, 0, 0);
                }
            }

        __syncthreads();                       // everyone done reading As
        if (more) { stageA(); stageB((s + 1) & 1); }
        __syncthreads();
    }

    lif_epi(acc, bias, memOut, sbitsOut, bm, bn, wm, wn, lane);
}

// ---------------------------------------------------------------------------
// Output layer: A = packed spike bits (uint per lane = 32 cols), wave per row.
// ---------------------------------------------------------------------------
__device__ __forceinline__ void role_out(const unsigned char* __restrict__ sbits,
    const float* __restrict__ wo, const float* __restrict__ bo,
    float* __restrict__ memo, float* __restrict__ ssum, int rb, int tid)
{
    const int lane = tid & 63, wvi = tid >> 6;
    const int b = rb * 4 + wvi;

    const unsigned int bits = *(const unsigned int*)(sbits + (size_t)b * (HID / 8) + lane * 4);
    float acc[NCLS];
#pragma unroll
    for (int c = 0; c < NCLS; c++) {
        const f4* wrow = (const f4*)(wo + (size_t)c * HID + lane * 32);
        float s = 0.f;
#pragma unroll
        for (int q = 0; q < 8; q++) {
            f4 w = wrow[q];
#pragma unroll
            for (int i = 0; i < 4; i++)
                if ((bits >> (q * 4 + i)) & 1u) s += w[i];
        }
        acc[c] = s;
    }
#pragma unroll
    for (int c = 0; c < NCLS; c++)
#pragma unroll
        for (int m = 1; m < 64; m <<= 1) acc[c] += __shfl_xor(acc[c], m, 64);

    if (lane == 0) {
#pragma unroll
        for (int c = 0; c < NCLS; c++) {
            float mo  = memo[b * NCLS + c];
            float rst = (mo > VTH) ? VTH : 0.f;
            float m2  = BETA * mo + acc[c] + bo[c] - rst;
            memo[b * NCLS + c] = m2;
            if (m2 > VTH) ssum[b * NCLS + c] += 1.f;
        }
    }
}

// ---------------------------------------------------------------------------
// V1 fused pipeline step (fallback)
// ---------------------------------------------------------------------------
__global__ __launch_bounds__(256)
void snn_step(const float* __restrict__ x,
              const float* __restrict__ w1, const float* __restrict__ m1, const float* __restrict__ b1,
              const unsigned short* __restrict__ w2h1, const unsigned short* __restrict__ w2h2,
              const unsigned short* __restrict__ w2h3, const float* __restrict__ b2,
              const unsigned short* __restrict__ w3h1, const unsigned short* __restrict__ w3h2,
              const unsigned short* __restrict__ w3h3,
              const float* __restrict__ w3f, const float* __restrict__ m3f,
              const float* __restrict__ b3,
              const float* __restrict__ wo, const float* __restrict__ bo,
              float* __restrict__ mem1, float* __restrict__ mem2, float* __restrict__ mem3,
              float* __restrict__ memo,
              unsigned char* __restrict__ spk1, unsigned char* __restrict__ spk2,
              unsigned char* __restrict__ spk3,
              float* __restrict__ ssum, int j)
{
    __shared__ __align__(16) unsigned char smem[46080];
    const int bid = blockIdx.x, tid = threadIdx.x;

    if (bid < 256) {
        const int t = j;
        if (t <= TSTEPS - 1)
            role_l1(smem, x + (size_t)t * BSZ * DIN, w1, m1, b1, mem1,
                    spk1 + (size_t)(t & 1) * SPKB, bid, tid);
    } else if (bid < 512) {
        const int t = j - 1;
        if (t >= 0 && t <= TSTEPS - 1)
            role_l23<false>(smem, spk1 + (size_t)(t & 1) * SPKB,
                            w2h1, w2h2, w2h3, nullptr, nullptr, b2, mem2,
                            spk2 + (size_t)(t & 1) * SPKB, bid - 256, tid);
    } else if (bid < 768) {
        const int t = j - 2;
        if (t >= 0 && t <= TSTEPS - 1) {
            if (w3h1)
                role_l23<false>(smem, spk2 + (size_t)(t & 1) * SPKB,
                                w3h1, w3h2, w3h3, nullptr, nullptr, b3, mem3,
                                spk3 + (size_t)(t & 1) * SPKB, bid - 512, tid);
            else
                role_l23<true>(smem, spk2 + (size_t)(t & 1) * SPKB,
                               nullptr, nullptr, nullptr, w3f, m3f, b3, mem3,
                               spk3 + (size_t)(t & 1) * SPKB, bid - 512, tid);
        }
    } else {
        const int t = j - 3;
        if (t >= 0 && t <= TSTEPS - 1)
            role_out(spk3 + (size_t)(t & 1) * SPKB, wo, bo, memo, ssum, bid - 768, tid);
    }
}

// ===========================================================================
// ===========================  V2 ROLE CODE  ================================
// ===========================================================================
__device__ __forceinline__ void role_l23b(unsigned char* smem,
    const unsigned char* __restrict__ sbitsIn,
    const unsigned short* __restrict__ Bp,      // 3 planes, stride HID*HID
    const float* __restrict__ bias, float* __restrict__ memOut,
    unsigned char* __restrict__ sbitsOut, int rb, int tid)
{
    auto Bs = reinterpret_cast<unsigned short(*)[3][64 * 40]>(smem);   // [2][3] = 30720 B
    const size_t PS = (size_t)HID * HID;

    const int bn = rb & 31, bm = rb >> 5;
    const int srow = tid >> 2, skq = tid & 3;
    const int lane = tid & 63, wv = tid >> 6;
    const int wm = wv >> 1, wn = wv & 1;
    const int fr = lane & 15, fk = (lane >> 4) * 8;
    const size_t bRow = (size_t)(bn * 64 + srow) * HID;
    const int sdst = srow * 40 + skq * 8;

    const unsigned char* aP0 = sbitsIn + (size_t)(bm * 64 + wm * 32 + fr) * (HID / 8);
    const unsigned char* aP1 = aP0 + (size_t)16 * (HID / 8);

    f32x4 acc[2][2] = {};
    us8 bb0, bb1, bb2;
    unsigned aw0, aw1;

    auto ldB = [&](int k0) {
        bb0 = *(const us8*)(Bp + bRow + k0 + skq * 8);
        bb1 = *(const us8*)(Bp + PS + bRow + k0 + skq * 8);
        bb2 = *(const us8*)(Bp + 2 * PS + bRow + k0 + skq * 8);
    };
    auto stage = [&](int nb) {
        *(us8*)&Bs[nb][0][sdst] = bb0;
        *(us8*)&Bs[nb][1][sdst] = bb1;
        *(us8*)&Bs[nb][2][sdst] = bb2;
    };

    ldB(0); stage(0);
    aw0 = *(const unsigned*)(aP0);
    aw1 = *(const unsigned*)(aP1);
    __syncthreads();

    const int nsteps = HID / 32;      // 64
    for (int s = 0; s < nsteps; s++) {
        const int buf = s & 1;
        const bool more = (s + 1 < nsteps);
        unsigned awn0 = 0, awn1 = 0;
        if (more) {
            ldB((s + 1) * 32);
            awn0 = *(const unsigned*)(aP0 + (s + 1) * 4);
            awn1 = *(const unsigned*)(aP1 + (s + 1) * 4);
        }

        bf16x8 af[2];
        {
            unsigned byt0 = aw0 >> fk, byt1 = aw1 >> fk;
            us8 e0, e1;
#pragma unroll
            for (int jj = 0; jj < 8; jj++) {
                e0[jj] = ((byt0 >> jj) & 1u) ? (unsigned short)0x3F80 : (unsigned short)0;
                e1[jj] = ((byt1 >> jj) & 1u) ? (unsigned short)0x3F80 : (unsigned short)0;
            }
            af[0] = *(bf16x8*)&e0;
            af[1] = *(bf16x8*)&e1;
        }

        bf16x8 bf[3][2];
#pragma unroll
        for (int fn = 0; fn < 2; fn++) {
            bf[0][fn] = *(const bf16x8*)&Bs[buf][0][(wn * 32 + fn * 16 + fr) * 40 + fk];
            bf[1][fn] = *(const bf16x8*)&Bs[buf][1][(wn * 32 + fn * 16 + fr) * 40 + fk];
            bf[2][fn] = *(const bf16x8*)&Bs[buf][2][(wn * 32 + fn * 16 + fr) * 40 + fk];
        }
#pragma unroll
        for (int fm = 0; fm < 2; fm++)
#pragma unroll
            for (int fn = 0; fn < 2; fn++) {
                acc[fm][fn] = __builtin_amdgcn_mfma_f32_16x16x32_bf16(af[fm], bf[0][fn], acc[fm][fn], 0, 0, 0);
                acc[fm][fn] = __builtin_amdgcn_mfma_f32_16x16x32_bf16(af[fm], bf[1][fn], acc[fm][fn], 0, 0, 0);
                acc[fm][fn] = __builtin_amdgcn_mfma_f32_16x16x32_bf16(af[fm], bf[2][fn], acc[fm][fn], 0, 0, 0);
            }

        if (more) { stage(buf ^ 1); aw0 = awn0; aw1 = awn1; }
        __syncthreads();
    }

    lif_epi(acc, bias, memOut, sbitsOut, bm, bn, wm, wn, lane);
}

__device__ __forceinline__ void role_l1p(unsigned char* smem,
    const unsigned short* __restrict__ Ap,      // 3 planes of x_t, stride BSZ*DIN
    const unsigned short* __restrict__ Wp,      // 3 planes of w1*m1, stride HID*DIN
    const float* __restrict__ bias, float* __restrict__ memOut,
    unsigned char* __restrict__ sbitsOut, int rb, int tid)
{
    auto As = reinterpret_cast<unsigned short(*)[64 * 40]>(smem);              // [3]
    auto Bs = reinterpret_cast<unsigned short(*)[3][64 * 40]>(smem + 15360);   // [2][3]
    const size_t APS = (size_t)BSZ * DIN;
    const size_t BPS = (size_t)HID * DIN;

    const int bn = rb & 31, bm = rb >> 5;
    const int srow = tid >> 2, skq = tid & 3;
    const int lane = tid & 63, wv = tid >> 6;
    const int wm = wv >> 1, wn = wv & 1;
    const int fr = lane & 15, fk = (lane >> 4) * 8;
    const size_t aRow = (size_t)(bm * 64 + srow) * DIN;
    const size_t bRow = (size_t)(bn * 64 + srow) * DIN;
    const int sdst = srow * 40 + skq * 8;

    f32x4 acc[2][2] = {};
    us8 aa0, aa1, aa2, bb0, bb1, bb2;

    auto ldnext = [&](int k0) {
        aa0 = *(const us8*)(Ap + aRow + k0 + skq * 8);
        aa1 = *(const us8*)(Ap + APS + aRow + k0 + skq * 8);
        aa2 = *(const us8*)(Ap + 2 * APS + aRow + k0 + skq * 8);
        bb0 = *(const us8*)(Wp + bRow + k0 + skq * 8);
        bb1 = *(const us8*)(Wp + BPS + bRow + k0 + skq * 8);
        bb2 = *(const us8*)(Wp + 2 * BPS + bRow + k0 + skq * 8);
    };
    auto stageA = [&]() {
        *(us8*)&As[0][sdst] = aa0;
        *(us8*)&As[1][sdst] = aa1;
        *(us8*)&As[2][sdst] = aa2;
    };
    auto stageB = [&](int nb) {
        *(us8*)&Bs[nb][0][sdst] = bb0;
        *(us8*)&Bs[nb][1][sdst] = bb1;
        *(us8*)&Bs[nb][2][sdst] = bb2;
    };

    ldnext(0); stageA(); stageB(0);
    __syncthreads();

    const int nsteps = DIN / 32;      // 32
    for (int s = 0; s < nsteps; s++) {
        const bool more = (s + 1 < nsteps);
        if (more) ldnext((s + 1) * 32);

        bf16x8 af[3][2], bf[3][2];
#pragma unroll
        for (int p = 0; p < 3; p++)
#pragma unroll
            for (int f = 0; f < 2; f++) {
                af[p][f] = *(const bf16x8*)&As[p][(wm * 32 + f * 16 + fr) * 40 + fk];
                bf[p][f] = *(const bf16x8*)&Bs[s & 1][p][(wn * 32 + f * 16 + fr) * 40 + fk];
            }
#pragma unroll
        for (int pa = 0; pa < 3; pa++)
#pragma unroll
            for (int pb = 0; pb < 3; pb++) {
                if (pa + pb <= 2) {
#pragma unroll
                    for (int fm = 0; fm < 2; fm++)
#pragma unroll
                        for (int fn = 0; fn < 2; fn++)
                            acc[fm][fn] = __builtin_amdgcn_mfma_f32_16x16x32_bf16(
                                af[pa][fm], bf[pb][fn], acc[fm][fn], 0, 0, 0);
                }
            }

        __syncthreads();
        if (more) { stageA(); stageB((s + 1) & 1); }
        __syncthreads();
    }

    lif_epi(acc, bias, memOut, sbitsOut, bm, bn, wm, wn, lane);
}

__global__ __launch_bounds__(256)
void snn_step2(const float* __restrict__ x,
               unsigned short* __restrict__ xp,
               const unsigned short* __restrict__ w1p, const float* __restrict__ b1,
               const unsigned short* __restrict__ w2p, const float* __restrict__ b2,
               const unsigned short* __restrict__ w3p, const float* __restrict__ b3,
               const float* __restrict__ wo, const float* __restrict__ bo,
               float* __restrict__ mem1, float* __restrict__ mem2, float* __restrict__ mem3,
               float* __restrict__ memo,
               unsigned char* __restrict__ spk1, unsigned char* __restrict__ spk2,
               unsigned char* __restrict__ spk3,
               float* __restrict__ ssum, int j)
{
    __shared__ __align__(16) unsigned char smem[46080];
    const int bid = blockIdx.x, tid = threadIdx.x;
    const size_t XSLOT = (size_t)3 * BSZ * DIN;

    if (bid < 256) {
        const int t = j;
        if (t <= TSTEPS - 1)
            role_l1p(smem, xp + (size_t)(t & 1) * XSLOT, w1p, b1, mem1,
                     spk1 + (size_t)(t & 1) * SPKB, bid, tid);
    } else if (bid < 512) {
        const int t = j - 1;
        if (t >= 0 && t <= TSTEPS - 1)
            role_l23b(smem, spk1 + (size_t)(t & 1) * SPKB, w2p, b2, mem2,
                      spk2 + (size_t)(t & 1) * SPKB, bid - 256, tid);
    } else if (bid < 768) {
        const int t = j - 2;
        if (t >= 0 && t <= TSTEPS - 1)
            role_l23b(smem, spk2 + (size_t)(t & 1) * SPKB, w3p, b3, mem3,
                      spk3 + (size_t)(t & 1) * SPKB, bid - 512, tid);
    } else {
        const int t1 = j + 1;
        if (t1 <= TSTEPS - 1)
            xsplit_dev(x + (size_t)t1 * BSZ * DIN,
                       xp + (size_t)(t1 & 1) * XSLOT, bid - 768, 128, tid);
        const int t = j - 3;
        if (t >= 0 && t <= TSTEPS - 1)
            role_out(spk3 + (size_t)(t & 1) * SPKB, wo, bo, memo, ssum, bid - 768, tid);
    }
}

// ===========================================================================
// ===========================  V3 ROLE CODE  ================================
// ===========================================================================

// Layers 2/3 v3: wave tile 64x16 (fm=4, fn=1). A = bf16 spikes loaded
// global->reg directly (no LDS tile, no bit expansion). B = 3 planes staged
// in dbuf LDS (30720 B) with 2-deep register prefetch (unroll-2, static sets).
__device__ __forceinline__ void role_l23c(unsigned char* smem,
    const unsigned short* __restrict__ spkIn,   // bf16 [BSZ][HID]
    const unsigned short* __restrict__ Bp,      // 3 planes, stride HID*HID
    const float* __restrict__ bias, float* __restrict__ memOut,
    unsigned char* __restrict__ sbitsOut, unsigned short* __restrict__ spkOut,
    int rb, int tid)
{
    auto Bs = reinterpret_cast<unsigned short(*)[3][64 * 40]>(smem);   // [2][3] = 30720 B
    const size_t PS = (size_t)HID * HID;

    const int bn = rb & 31, bm = rb >> 5;
    const int srow = tid >> 2, skq = tid & 3;
    const int lane = tid & 63, wv = tid >> 6;          // wv = fn-block (16 cols)
    const int fr = lane & 15, fk = (lane >> 4) * 8;
    const size_t bRow = (size_t)(bn * 64 + srow) * HID;
    const int sdst = srow * 40 + skq * 8;
    const unsigned short* aBase = spkIn + (size_t)(bm * 64 + fr) * HID + fk;

    f32x4 acc[4] = {};
    us8 bb[2][3];      // B prefetch sets (literal-indexed only)
    us8 af[2][4];      // A cur/next sets (literal-indexed only)

#define LDB_(SET, K0) do {                                              \
        bb[SET][0] = *(const us8*)(Bp + bRow + (K0) + skq * 8);         \
        bb[SET][1] = *(const us8*)(Bp + PS + bRow + (K0) + skq * 8);    \
        bb[SET][2] = *(const us8*)(Bp + 2 * PS + bRow + (K0) + skq * 8);\
    } while (0)
#define LDA_(SET, S) do {                                               \
        af[SET][0] = *(const us8*)(aBase + 0 * 16 * HID + (S) * 32);    \
        af[SET][1] = *(const us8*)(aBase + 1 * 16 * HID + (S) * 32);    \
        af[SET][2] = *(const us8*)(aBase + 2 * 16 * HID + (S) * 32);    \
        af[SET][3] = *(const us8*)(aBase + 3 * 16 * HID + (S) * 32);    \
    } while (0)
#define STAGE_(BUF, SET) do {                                           \
        *(us8*)&Bs[BUF][0][sdst] = bb[SET][0];                          \
        *(us8*)&Bs[BUF][1][sdst] = bb[SET][1];                          \
        *(us8*)&Bs[BUF][2][sdst] = bb[SET][2];                          \
    } while (0)
#define COMPUTE_(BUF, ASET) do {                                                        \
        bf16x8 b0_ = *(const bf16x8*)&Bs[BUF][0][(wv * 16 + fr) * 40 + fk];             \
        bf16x8 b1_ = *(const bf16x8*)&Bs[BUF][1][(wv * 16 + fr) * 40 + fk];             \
        bf16x8 b2_ = *(const bf16x8*)&Bs[BUF][2][(wv * 16 + fr) * 40 + fk];             \
        bf16x8 a0_ = *(const bf16x8*)&af[ASET][0];                                      \
        bf16x8 a1_ = *(const bf16x8*)&af[ASET][1];                                      \
        bf16x8 a2_ = *(const bf16x8*)&af[ASET][2];                                      \
        bf16x8 a3_ = *(const bf16x8*)&af[ASET][3];                                      \
        acc[0] = __builtin_amdgcn_mfma_f32_16x16x32_bf16(a0_, b0_, acc[0], 0, 0, 0);    \
        acc[0] = __builtin_amdgcn_mfma_f32_16x16x32_bf16(a0_, b1_, acc[0], 0, 0, 0);    \
        acc[0] = __builtin_amdgcn_mfma_f32_16x16x32_bf16(a0_, b2_, acc[0], 0, 0, 0);    \
        acc[1] = __builtin_amdgcn_mfma_f32_16x16x32_bf16(a1_, b0_, acc[1], 0, 0, 0);    \
        acc[1] = __builtin_amdgcn_mfma_f32_16x16x32_bf16(a1_, b1_, acc[1], 0, 0, 0);    \
        acc[1] = __builtin_amdgcn_mfma_f32_16x16x32_bf16(a1_, b2_, acc[1], 0, 0, 0);    \
        acc[2] = __builtin_amdgcn_mfma_f32_16x16x32_bf16(a2_, b0_, acc[2], 0, 0, 0);    \
        acc[2] = __builtin_amdgcn_mfma_f32_16x16x32_bf16(a2_, b1_, acc[2], 0, 0, 0);    \
        acc[2] = __builtin_amdgcn_mfma_f32_16x16x32_bf16(a2_, b2_, acc[2], 0, 0, 0);    \
        acc[3] = __builtin_amdgcn_mfma_f32_16x16x32_bf16(a3_, b0_, acc[3], 0, 0, 0);    \
        acc[3] = __builtin_amdgcn_mfma_f32_16x16x32_bf16(a3_, b1_, acc[3], 0, 0, 0);    \
        acc[3] = __builtin_amdgcn_mfma_f32_16x16x32_bf16(a3_, b2_, acc[3], 0, 0, 0);    \
    } while (0)

    LDB_(0, 0);
    STAGE_(0, 0);           // waits P's loads
    LDB_(1, 32);            // Q = data for step 1, in flight across barrier
    LDA_(0, 0);
    __syncthreads();

    for (int s = 0; s < 64; s += 2) {
        // ---- even step s: read buf0, A set0; Q(set1) holds s+1 data
        if (s + 2 < 64) LDB_(0, (s + 2) * 32);
        LDA_(1, s + 1);                     // s+1 <= 63 always
        COMPUTE_(0, 0);
        STAGE_(1, 1);                       // stage s+1 (loads issued a full step ago)
        __syncthreads();
        // ---- odd step s+1: read buf1, A set1; P(set0) holds s+2 data
        if (s + 3 < 64) LDB_(1, (s + 3) * 32);
        if (s + 2 < 64) LDA_(0, s + 2);
        COMPUTE_(1, 1);
        if (s + 2 < 64) STAGE_(0, 0);
        __syncthreads();
    }

#undef LDB_
#undef LDA_
#undef STAGE_
#undef COMPUTE_

    lif_epi4(acc, bias, memOut, sbitsOut, spkOut, bm, bn, wv, lane);
}

// Layer 1 v3: same as role_l1p but single-buffered Bs (30720 B total LDS)
// and bf16 spike output.
__device__ __forceinline__ void role_l1q(unsigned char* smem,
    const unsigned short* __restrict__ Ap,      // 3 planes of x_t, stride BSZ*DIN
    const unsigned short* __restrict__ Wp,      // 3 planes of w1*m1, stride HID*DIN
    const float* __restrict__ bias, float* __restrict__ memOut,
    unsigned short* __restrict__ spkOut, int rb, int tid)
{
    auto As = reinterpret_cast<unsigned short(*)[64 * 40]>(smem);              // [3]
    auto Bs = reinterpret_cast<unsigned short(*)[64 * 40]>(smem + 15360);      // [3]
    const size_t APS = (size_t)BSZ * DIN;
    const size_t BPS = (size_t)HID * DIN;

    const int bn = rb & 31, bm = rb >> 5;
    const int srow = tid >> 2, skq = tid & 3;
    const int lane = tid & 63, wv = tid >> 6;
    const int wm = wv >> 1, wn = wv & 1;
    const int fr = lane & 15, fk = (lane >> 4) * 8;
    const size_t aRow = (size_t)(bm * 64 + srow) * DIN;
    const size_t bRow = (size_t)(bn * 64 + srow) * DIN;
    const int sdst = srow * 40 + skq * 8;

    f32x4 acc[2][2] = {};
    us8 aa0, aa1, aa2, bb0, bb1, bb2;

    auto ldnext = [&](int k0) {
        aa0 = *(const us8*)(Ap + aRow + k0 + skq * 8);
        aa1 = *(const us8*)(Ap + APS + aRow + k0 + skq * 8);
        aa2 = *(const us8*)(Ap + 2 * APS + aRow + k0 + skq * 8);
        bb0 = *(const us8*)(Wp + bRow + k0 + skq * 8);
        bb1 = *(const us8*)(Wp + BPS + bRow + k0 + skq * 8);
        bb2 = *(const us8*)(Wp + 2 * BPS + bRow + k0 + skq * 8);
    };
    auto stageAB = [&]() {
        *(us8*)&As[0][sdst] = aa0;
        *(us8*)&As[1][sdst] = aa1;
        *(us8*)&As[2][sdst] = aa2;
        *(us8*)&Bs[0][sdst] = bb0;
        *(us8*)&Bs[1][sdst] = bb1;
        *(us8*)&Bs[2][sdst] = bb2;
    };

    ldnext(0); stageAB();
    __syncthreads();

    const int nsteps = DIN / 32;      // 32
    for (int s = 0; s < nsteps; s++) {
        const bool more = (s + 1 < nsteps);
        if (more) ldnext((s + 1) * 32);

        bf16x8 af[3][2], bf[3][2];
#pragma unroll
        for (int p = 0; p < 3; p++)
#pragma unroll
            for (int f = 0; f < 2; f++) {
                af[p][f] = *(const bf16x8*)&As[p][(wm * 32 + f * 16 + fr) * 40 + fk];
                bf[p][f] = *(const bf16x8*)&Bs[p][(wn * 32 + f * 16 + fr) * 40 + fk];
            }
#pragma unroll
        for (int pa = 0; pa < 3; pa++)
#pragma unroll
            for (int pb = 0; pb < 3; pb++) {
                if (pa + pb <= 2) {
#pragma unroll
                    for (int fm = 0; fm < 2; fm++)
#pragma unroll
                        for (int fn = 0; fn < 2; fn++)
                            acc[fm][fn] = __builtin_amdgcn_mfma_f32_16x16x32_bf16(
                                af[pa][fm], bf[pb][fn], acc[fm][fn], 0, 0, 0);
                }
            }

        __syncthreads();                       // everyone done reading
        if (more) stageAB();
        __syncthreads();
    }

    lif_epi_bf(acc, bias, memOut, spkOut, bm, bn, wm, wn, lane);
}

// ---------------------------------------------------------------------------
// V3 fused pipeline step (diagonal j):
//   XS(t=j+1) | L1(t=j) | L2(t=j-1) | L3(t=j-2) | OUT(t=j-3)
// spk1/spk2 are bf16 [2][BSZ][HID]; spk3 stays packed bitmap for OUT.
// LDS 30720 B -> 4-5 blocks/CU.
// ---------------------------------------------------------------------------
__global__ __launch_bounds__(256, 4)
void snn_step3(const float* __restrict__ x,
               unsigned short* __restrict__ xp,
               const unsigned short* __restrict__ w1p, const float* __restrict__ b1,
               const unsigned short* __restrict__ w2p, const float* __restrict__ b2,
               const unsigned short* __restrict__ w3p, const float* __restrict__ b3,
               const float* __restrict__ wo, const float* __restrict__ bo,
               float* __restrict__ mem1, float* __restrict__ mem2, float* __restrict__ mem3,
               float* __restrict__ memo,
               unsigned short* __restrict__ spk1b, unsigned short* __restrict__ spk2b,
               unsigned char* __restrict__ spk3,
               float* __restrict__ ssum, int j)
{
    __shared__ __align__(16) unsigned char smem[30720];
    const int bid = blockIdx.x, tid = threadIdx.x;
    const size_t XSLOT = (size_t)3 * BSZ * DIN;
    const size_t SBF   = (size_t)BSZ * HID;

    if (bid < 256) {
        const int t = j;
        if (t <= TSTEPS - 1)
            role_l1q(smem, xp + (size_t)(t & 1) * XSLOT, w1p, b1, mem1,
                     spk1b + (size_t)(t & 1) * SBF, bid, tid);
    } else if (bid < 512) {
        const int t = j - 1;
        if (t >= 0 && t <= TSTEPS - 1)
            role_l23c(smem, spk1b + (size_t)(t & 1) * SBF, w2p, b2, mem2,
                      nullptr, spk2b + (size_t)(t & 1) * SBF, bid - 256, tid);
    } else if (bid < 768) {
        const int t = j - 2;
        if (t >= 0 && t <= TSTEPS - 1)
            role_l23c(smem, spk2b + (size_t)(t & 1) * SBF, w3p, b3, mem3,
                      spk3 + (size_t)(t & 1) * SPKB, nullptr, bid - 512, tid);
    } else {
        const int t1 = j + 1;
        if (t1 <= TSTEPS - 1)
            xsplit_dev(x + (size_t)t1 * BSZ * DIN,
                       xp + (size_t)(t1 & 1) * XSLOT, bid - 768, 128, tid);
        const int t = j - 3;
        if (t >= 0 && t <= TSTEPS - 1)
            role_out(spk3 + (size_t)(t & 1) * SPKB, wo, bo, memo, ssum, bid - 768, tid);
    }
}

// ---------------------------------------------------------------------------
extern "C" void kernel_launch(void* const* d_in, const int* in_sizes, int n_in,
                              void* d_out, int out_size, void* d_ws, size_t ws_size,
                              hipStream_t stream)
{
    const float* x  = (const float*)d_in[0];
    const float* w1 = (const float*)d_in[1];
    const float* b1 = (const float*)d_in[2];
    const float* m1 = (const float*)d_in[3];
    const float* w2 = (const float*)d_in[4];
    const float* b2 = (const float*)d_in[5];
    const float* m2 = (const float*)d_in[6];
    const float* w3 = (const float*)d_in[7];
    const float* b3 = (const float*)d_in[8];
    const float* m3 = (const float*)d_in[9];
    const float* wo = (const float*)d_in[10];
    const float* bo = (const float*)d_in[11];
    float* out = (float*)d_out;

    const size_t planeB  = (size_t)HID * HID * 2;   // 8,388,608
    const size_t plane1B = (size_t)HID * DIN * 2;   // 4,194,304
    const size_t planeXB = (size_t)BSZ * DIN * 2;   // 1,048,576
    const size_t memB    = (size_t)BSZ * HID * 4;   // 4,194,304
    const size_t memoB   = (size_t)BSZ * NCLS * 4;  // 20,480
    const size_t spk2B   = 2 * SPKB;                // 262,144
    const size_t spkbfB  = 2 * (size_t)BSZ * HID * 2;  // 4,194,304 (2 slots bf16)

    unsigned char* base = (unsigned char*)d_ws;

    const size_t needV3 = 6 * planeB + 3 * plane1B + 6 * planeXB
                        + 3 * memB + memoB + 2 * spkbfB + spk2B;   // 90,460,160

    if (ws_size >= needV3) {
        // ---------------- V3 path ----------------
        unsigned short* w2p = (unsigned short*)base;
        unsigned short* w3p = (unsigned short*)(base + 3 * planeB);
        unsigned short* w1p = (unsigned short*)(base + 6 * planeB);
        unsigned short* xp  = (unsigned short*)(base + 6 * planeB + 3 * plane1B);
        unsigned char* mbase = base + 6 * planeB + 3 * plane1B + 6 * planeXB;
        float* mem1 = (float*)(mbase);
        float* mem2 = (float*)(mbase + memB);
        float* mem3 = (float*)(mbase + 2 * memB);
        float* memo = (float*)(mbase + 3 * memB);
        unsigned short* spk1b = (unsigned short*)(mbase + 3 * memB + memoB);
        unsigned short* spk2b = spk1b + 2 * (size_t)BSZ * HID;
        unsigned char*  spk3  = (unsigned char*)(spk2b + 2 * (size_t)BSZ * HID);

        const int nW23 = HID * HID / 4;
        const int nW1  = HID * DIN / 4;
        const size_t HH = (size_t)HID * HID;
        const size_t HD = (size_t)HID * DIN;
        split3<<<1024, 256, 0, stream>>>(w2, m2, w2p, w2p + HH, w2p + 2 * HH, nW23);
        split3<<<1024, 256, 0, stream>>>(w3, m3, w3p, w3p + HH, w3p + 2 * HH, nW23);
        split3<<<1024, 256, 0, stream>>>(w1, m1, w1p, w1p + HD, w1p + 2 * HD, nW1);
        xsplit_k<<<256, 256, 0, stream>>>(x, xp);   // t=0 into slot 0

        zerof<<<1024, 256, 0, stream>>>(mem1, (int)((3 * memB + memoB) / 16));
        zerof<<<8, 256, 0, stream>>>(out, (BSZ * NCLS) / 4);

        for (int j = 0; j <= TSTEPS + 2; j++) {   // 35 diagonals
            snn_step3<<<896, 256, 0, stream>>>(x, xp, w1p, b1, w2p, b2, w3p, b3,
                                               wo, bo, mem1, mem2, mem3, memo,
                                               spk1b, spk2b, spk3, out, j);
        }
        return;
    }

    const size_t needV2 = 6 * planeB + 3 * plane1B + 6 * planeXB
                        + 3 * memB + memoB + 3 * spk2B;          // 82,595,840

    if (ws_size >= needV2) {
        // ---------------- V2 path ----------------
        unsigned short* w2p = (unsigned short*)base;
        unsigned short* w3p = (unsigned short*)(base + 3 * planeB);
        unsigned short* w1p = (unsigned short*)(base + 6 * planeB);
        unsigned short* xp  = (unsigned short*)(base + 6 * planeB + 3 * plane1B);
        unsigned char* mbase = base + 6 * planeB + 3 * plane1B + 6 * planeXB;
        float* mem1 = (float*)(mbase);
        float* mem2 = (float*)(mbase + memB);
        float* mem3 = (float*)(mbase + 2 * memB);
        float* memo = (float*)(mbase + 3 * memB);
        unsigned char* spk1 = mbase + 3 * memB + memoB;
        unsigned char* spk2 = spk1 + spk2B;
        unsigned char* spk3 = spk2 + spk2B;

        const int nW23 = HID * HID / 4;
        const int nW1  = HID * DIN / 4;
        const size_t HH = (size_t)HID * HID;
        const size_t HD = (size_t)HID * DIN;
        split3<<<1024, 256, 0, stream>>>(w2, m2, w2p, w2p + HH, w2p + 2 * HH, nW23);
        split3<<<1024, 256, 0, stream>>>(w3, m3, w3p, w3p + HH, w3p + 2 * HH, nW23);
        split3<<<1024, 256, 0, stream>>>(w1, m1, w1p, w1p + HD, w1p + 2 * HD, nW1);
        xsplit_k<<<256, 256, 0, stream>>>(x, xp);

        zerof<<<1024, 256, 0, stream>>>(mem1, (int)((3 * memB + memoB) / 16));
        zerof<<<8, 256, 0, stream>>>(out, (BSZ * NCLS) / 4);

        for (int j = 0; j <= TSTEPS + 2; j++) {
            snn_step2<<<896, 256, 0, stream>>>(x, xp, w1p, b1, w2p, b2, w3p, b3,
                                               wo, bo, mem1, mem2, mem3, memo,
                                               spk1, spk2, spk3, out, j);
        }
        return;
    }

    // ---------------- V1 fallback ----------------
    const size_t needBoth = 6 * planeB + 3 * memB + memoB + 3 * spk2B;  // 63,721,472
    const bool both = ws_size >= needBoth;
    const int nPlanes = both ? 6 : 3;

    unsigned short* w2h1 = (unsigned short*)(base + 0 * planeB);
    unsigned short* w2h2 = (unsigned short*)(base + 1 * planeB);
    unsigned short* w2h3 = (unsigned short*)(base + 2 * planeB);
    unsigned short* w3h1 = both ? (unsigned short*)(base + 3 * planeB) : nullptr;
    unsigned short* w3h2 = both ? (unsigned short*)(base + 4 * planeB) : nullptr;
    unsigned short* w3h3 = both ? (unsigned short*)(base + 5 * planeB) : nullptr;
    unsigned char* mbase = base + (size_t)nPlanes * planeB;
    float* mem1 = (float*)(mbase);
    float* mem2 = (float*)(mbase + memB);
    float* mem3 = (float*)(mbase + 2 * memB);
    float* memo = (float*)(mbase + 3 * memB);
    unsigned char* spk1 = mbase + 3 * memB + memoB;
    unsigned char* spk2 = spk1 + spk2B;
    unsigned char* spk3 = spk2 + spk2B;

    const int nW23 = HID * HID / 4;
    split3<<<1024, 256, 0, stream>>>(w2, m2, w2h1, w2h2, w2h3, nW23);
    if (both) split3<<<1024, 256, 0, stream>>>(w3, m3, w3h1, w3h2, w3h3, nW23);

    zerof<<<1024, 256, 0, stream>>>(mem1, (int)((3 * memB + memoB) / 16));
    zerof<<<8, 256, 0, stream>>>(out, (BSZ * NCLS) / 4);

    for (int j = 0; j <= TSTEPS + 2; j++) {
        snn_step<<<896, 256, 0, stream>>>(x, w1, m1, b1,
                                          w2h1, w2h2, w2h3, b2,
                                          w3h1, w3h2, w3h3, w3, m3, b3,
                                          wo, bo,
                                          mem1, mem2, mem3, memo,
                                          spk1, spk2, spk3,
                                          out, j);
    }
}

// Round 4
// 1737.804 us; speedup vs baseline: 1.8955x; 1.8955x over previous
//
#include <hip/hip_runtime.h>

#define TSTEPS 32
#define BSZ    512
#define DIN    1024
#define HID    2048
#define NCLS   10
#define BETA   0.95f
#define VTH    1.0f
#define SPKB   ((size_t)BSZ * (HID / 8))   // 131072 B: one parity buffer of packed spikes

typedef __attribute__((ext_vector_type(4))) float          f4;
typedef __attribute__((ext_vector_type(4))) float          f32x4;
typedef __attribute__((ext_vector_type(8))) __bf16         bf16x8;
typedef __attribute__((ext_vector_type(8))) unsigned short us8;
typedef __attribute__((ext_vector_type(4))) unsigned short us4;
typedef __attribute__((ext_vector_type(2))) unsigned int   u32x2;

__device__ inline unsigned short f2bf(float f) {
    unsigned u = __float_as_uint(f);
    u += 0x7FFF + ((u >> 16) & 1);          // RNE
    return (unsigned short)(u >> 16);
}
__device__ inline float bf2f(unsigned short h) {
    return __uint_as_float(((unsigned)h) << 16);
}

// split e (8 floats in two f4) into 3 exact bf16 planes
__device__ __forceinline__ void split_f4pair(f4 v0, f4 v1, us8& o0, us8& o1, us8& o2) {
#pragma unroll
    for (int jj = 0; jj < 4; jj++) {
        float v = v0[jj];
        unsigned short h1 = f2bf(v); float r = v - bf2f(h1);
        unsigned short h2 = f2bf(r); float r2 = r - bf2f(h2);
        o0[jj] = h1; o1[jj] = h2; o2[jj] = f2bf(r2);
        v = v1[jj];
        h1 = f2bf(v); r = v - bf2f(h1);
        h2 = f2bf(r); r2 = r - bf2f(h2);
        o0[jj + 4] = h1; o1[jj + 4] = h2; o2[jj + 4] = f2bf(r2);
    }
}

// ---------------------------------------------------------------------------
// linear 3-plane split (w*m), row-major layout
// ---------------------------------------------------------------------------
__global__ __launch_bounds__(256)
void split3(const float* __restrict__ w, const float* __restrict__ m,
            unsigned short* __restrict__ h1, unsigned short* __restrict__ h2,
            unsigned short* __restrict__ h3, int n4)
{
    int i      = blockIdx.x * blockDim.x + threadIdx.x;
    int stride = gridDim.x * blockDim.x;
    for (; i < n4; i += stride) {
        f4 wv = ((const f4*)w)[i];
        f4 mv = ((const f4*)m)[i];
        us4 a, b, c;
#pragma unroll
        for (int j = 0; j < 4; j++) {
            float e  = wv[j] * mv[j];
            unsigned short x1 = f2bf(e);
            float r  = e - bf2f(x1);
            unsigned short x2 = f2bf(r);
            float r2 = r - bf2f(x2);
            a[j] = x1; b[j] = x2; c[j] = f2bf(r2);
        }
        ((us4*)h1)[i] = a;
        ((us4*)h2)[i] = b;
        ((us4*)h3)[i] = c;
    }
}

// ---------------------------------------------------------------------------
// swizzled 3-plane split for [HID][HID] weights: fragment-major output.
// frag(n_tile,k_tile): lane l holds w[n_tile*16+(l&15)][k_tile*32+(l>>4)*8 ..+8]
// offset (us8 units) = (n_tile*(HID/32) + k_tile)*64 + lane  == gid
// ---------------------------------------------------------------------------
__global__ __launch_bounds__(256)
void split3q(const float* __restrict__ w, const float* __restrict__ m,
             unsigned short* __restrict__ q)
{
    const int NK = HID * HID;
    int gid = blockIdx.x * 256 + threadIdx.x;          // 524288 threads = NK/8
    const int lane = gid & 63;
    const int t    = gid >> 6;
    const int kt   = t & (HID / 32 - 1);               // & 63
    const int nt   = t >> 6;
    const int n = nt * 16 + (lane & 15);
    const int k = kt * 32 + (lane >> 4) * 8;
    const size_t src = (size_t)n * HID + k;
    f4 w0 = *(const f4*)(w + src),     w1v = *(const f4*)(w + src + 4);
    f4 m0 = *(const f4*)(m + src),     m1v = *(const f4*)(m + src + 4);
    us8 q0, q1, q2;
    split_f4pair(w0 * m0, w1v * m1v, q0, q1, q2);
    ((us8*)q)[gid]            = q0;
    ((us8*)(q + NK))[gid]     = q1;
    ((us8*)(q + 2 * NK))[gid] = q2;
}

__global__ __launch_bounds__(256)
void zerof(float* __restrict__ p, int n4)
{
    int i      = blockIdx.x * blockDim.x + threadIdx.x;
    int stride = gridDim.x * blockDim.x;
    f4 z = {0.f, 0.f, 0.f, 0.f};
    for (; i < n4; i += stride) ((f4*)p)[i] = z;
}

// split x_t (no mask) into 3 bf16 planes (linear, plane stride BSZ*DIN)
__device__ __forceinline__ void xsplit_dev(const float* __restrict__ xt,
                                           unsigned short* __restrict__ dst,
                                           int bid, int nblk, int tid)
{
    const int n4 = BSZ * DIN / 4;              // 131072
    const int PS = BSZ * DIN;
    int i      = bid * 256 + tid;
    int stride = nblk * 256;
    for (; i < n4; i += stride) {
        f4 v = ((const f4*)xt)[i];
        us4 a, b, c;
#pragma unroll
        for (int j = 0; j < 4; j++) {
            float e = v[j];
            unsigned short x1 = f2bf(e);
            float r  = e - bf2f(x1);
            unsigned short x2 = f2bf(r);
            float r2 = r - bf2f(x2);
            a[j] = x1; b[j] = x2; c[j] = f2bf(r2);
        }
        ((us4*)(dst))[i]          = a;
        ((us4*)(dst + PS))[i]     = b;
        ((us4*)(dst + 2 * PS))[i] = c;
    }
}

__global__ __launch_bounds__(256)
void xsplit_k(const float* __restrict__ xt, unsigned short* __restrict__ dst)
{
    xsplit_dev(xt, dst, blockIdx.x, gridDim.x, threadIdx.x);
}

// ---------------------------------------------------------------------------
// LIF epilogue (2x2 wave tile): mem RMW + ballot-packed spike bits
// C/D mapping (verified m89/m91): col = lane&15, row = (lane>>4)*4 + reg
// ---------------------------------------------------------------------------
__device__ __forceinline__ void lif_epi(const f32x4 acc[2][2], const float* __restrict__ bias,
                                        float* __restrict__ memOut, unsigned char* __restrict__ sbits,
                                        int bm, int bn, int wm, int wn, int lane)
{
    const int fr = lane & 15;
#pragma unroll
    for (int fm = 0; fm < 2; fm++)
#pragma unroll
        for (int fn = 0; fn < 2; fn++) {
            const int n  = bn * 64 + wn * 32 + fn * 16 + fr;
            const float bv = bias[n];
            const int rbase = bm * 64 + wm * 32 + fm * 16 + (lane >> 4) * 4;
#pragma unroll
            for (int r = 0; r < 4; r++) {
                const int row = rbase + r;
                float* mp = memOut + (size_t)row * HID + n;
                float mo  = *mp;
                float m2  = BETA * mo + (acc[fm][fn][r] + bv) - ((mo > VTH) ? VTH : 0.f);
                *mp = m2;
                unsigned long long bal = __ballot(m2 > VTH);
                if (fr == 0) {  // lanes 0,16,32,48: each writes its own row's 16 col-bits
                    unsigned short bits = (unsigned short)(bal >> ((lane >> 4) * 16));
                    *(unsigned short*)(sbits + (size_t)row * (HID / 8) + bn * 8 + wn * 4 + fn * 2) = bits;
                }
            }
        }
}

// LIF epilogue for 64x16 wave tile (acc[fm], fm=0..3; wave wv owns 16 cols),
// ballot-bitmap output. Verified correct in the R2 kernel (v3 L3 path).
__device__ __forceinline__ void lif_epi4b(const f32x4 (&acc)[4], const float* __restrict__ bias,
                                          float* __restrict__ memOut,
                                          unsigned char* __restrict__ sbitsOut,
                                          int bm, int bn, int wv, int lane)
{
    const int fr = lane & 15;
    const int n  = bn * 64 + wv * 16 + fr;
    const float bv = bias[n];
#pragma unroll
    for (int fm = 0; fm < 4; fm++) {
        const int rbase = bm * 64 + fm * 16 + (lane >> 4) * 4;
#pragma unroll
        for (int r = 0; r < 4; r++) {
            const int row = rbase + r;
            float* mp = memOut + (size_t)row * HID + n;
            float mo  = *mp;
            float m2  = BETA * mo + (acc[fm][r] + bv) - ((mo > VTH) ? VTH : 0.f);
            *mp = m2;
            unsigned long long bal = __ballot(m2 > VTH);
            if (fr == 0) {
                unsigned short bits = (unsigned short)(bal >> ((lane >> 4) * 16));
                *(unsigned short*)(sbitsOut + (size_t)row * (HID / 8) + bn * 8 + wv * 2) = bits;
            }
        }
    }
}

// ---------------------------------------------------------------------------
// Output layer: A = packed spike bits (uint per lane = 32 cols), wave per row.
// ---------------------------------------------------------------------------
__device__ __forceinline__ void role_out_b(const unsigned char* __restrict__ sbits,
    const float* __restrict__ wo, const float* __restrict__ bo,
    float* __restrict__ memo, float* __restrict__ ssum, int b, int lane)
{
    const unsigned int bits = *(const unsigned int*)(sbits + (size_t)b * (HID / 8) + lane * 4);
    float acc[NCLS];
#pragma unroll
    for (int c = 0; c < NCLS; c++) {
        const f4* wrow = (const f4*)(wo + (size_t)c * HID + lane * 32);
        float s = 0.f;
#pragma unroll
        for (int q = 0; q < 8; q++) {
            f4 w = wrow[q];
#pragma unroll
            for (int i = 0; i < 4; i++)
                if ((bits >> (q * 4 + i)) & 1u) s += w[i];
        }
        acc[c] = s;
    }
#pragma unroll
    for (int c = 0; c < NCLS; c++)
#pragma unroll
        for (int m = 1; m < 64; m <<= 1) acc[c] += __shfl_xor(acc[c], m, 64);

    if (lane == 0) {
#pragma unroll
        for (int c = 0; c < NCLS; c++) {
            float mo  = memo[b * NCLS + c];
            float rst = (mo > VTH) ? VTH : 0.f;
            float m2  = BETA * mo + acc[c] + bo[c] - rst;
            memo[b * NCLS + c] = m2;
            if (m2 > VTH) ssum[b * NCLS + c] += 1.f;
        }
    }
}

// ===========================================================================
// ===========================  V2 ROLE CODE (fallback) ======================
// ===========================================================================
__device__ __forceinline__ void role_l23b(unsigned char* smem,
    const unsigned char* __restrict__ sbitsIn,
    const unsigned short* __restrict__ Bp,      // 3 linear planes, stride HID*HID
    const float* __restrict__ bias, float* __restrict__ memOut,
    unsigned char* __restrict__ sbitsOut, int rb, int tid)
{
    auto Bs = reinterpret_cast<unsigned short(*)[3][64 * 40]>(smem);   // [2][3] = 30720 B
    const size_t PS = (size_t)HID * HID;

    const int bn = rb & 31, bm = rb >> 5;
    const int srow = tid >> 2, skq = tid & 3;
    const int lane = tid & 63, wv = tid >> 6;
    const int wm = wv >> 1, wn = wv & 1;
    const int fr = lane & 15, fk = (lane >> 4) * 8;
    const size_t bRow = (size_t)(bn * 64 + srow) * HID;
    const int sdst = srow * 40 + skq * 8;

    const unsigned char* aP0 = sbitsIn + (size_t)(bm * 64 + wm * 32 + fr) * (HID / 8);
    const unsigned char* aP1 = aP0 + (size_t)16 * (HID / 8);

    f32x4 acc[2][2] = {};
    us8 bb0, bb1, bb2;
    unsigned aw0, aw1;

    auto ldB = [&](int k0) {
        bb0 = *(const us8*)(Bp + bRow + k0 + skq * 8);
        bb1 = *(const us8*)(Bp + PS + bRow + k0 + skq * 8);
        bb2 = *(const us8*)(Bp + 2 * PS + bRow + k0 + skq * 8);
    };
    auto stage = [&](int nb) {
        *(us8*)&Bs[nb][0][sdst] = bb0;
        *(us8*)&Bs[nb][1][sdst] = bb1;
        *(us8*)&Bs[nb][2][sdst] = bb2;
    };

    ldB(0); stage(0);
    aw0 = *(const unsigned*)(aP0);
    aw1 = *(const unsigned*)(aP1);
    __syncthreads();

    const int nsteps = HID / 32;      // 64
    for (int s = 0; s < nsteps; s++) {
        const int buf = s & 1;
        const bool more = (s + 1 < nsteps);
        unsigned awn0 = 0, awn1 = 0;
        if (more) {
            ldB((s + 1) * 32);
            awn0 = *(const unsigned*)(aP0 + (s + 1) * 4);
            awn1 = *(const unsigned*)(aP1 + (s + 1) * 4);
        }

        bf16x8 af[2];
        {
            unsigned byt0 = aw0 >> fk, byt1 = aw1 >> fk;
            us8 e0, e1;
#pragma unroll
            for (int jj = 0; jj < 8; jj++) {
                e0[jj] = ((byt0 >> jj) & 1u) ? (unsigned short)0x3F80 : (unsigned short)0;
                e1[jj] = ((byt1 >> jj) & 1u) ? (unsigned short)0x3F80 : (unsigned short)0;
            }
            af[0] = *(bf16x8*)&e0;
            af[1] = *(bf16x8*)&e1;
        }

        bf16x8 bf[3][2];
#pragma unroll
        for (int fn = 0; fn < 2; fn++) {
            bf[0][fn] = *(const bf16x8*)&Bs[buf][0][(wn * 32 + fn * 16 + fr) * 40 + fk];
            bf[1][fn] = *(const bf16x8*)&Bs[buf][1][(wn * 32 + fn * 16 + fr) * 40 + fk];
            bf[2][fn] = *(const bf16x8*)&Bs[buf][2][(wn * 32 + fn * 16 + fr) * 40 + fk];
        }
#pragma unroll
        for (int fm = 0; fm < 2; fm++)
#pragma unroll
            for (int fn = 0; fn < 2; fn++) {
                acc[fm][fn] = __builtin_amdgcn_mfma_f32_16x16x32_bf16(af[fm], bf[0][fn], acc[fm][fn], 0, 0, 0);
                acc[fm][fn] = __builtin_amdgcn_mfma_f32_16x16x32_bf16(af[fm], bf[1][fn], acc[fm][fn], 0, 0, 0);
                acc[fm][fn] = __builtin_amdgcn_mfma_f32_16x16x32_bf16(af[fm], bf[2][fn], acc[fm][fn], 0, 0, 0);
            }

        if (more) { stage(buf ^ 1); aw0 = awn0; aw1 = awn1; }
        __syncthreads();
    }

    lif_epi(acc, bias, memOut, sbitsOut, bm, bn, wm, wn, lane);
}

__device__ __forceinline__ void role_l1p(unsigned char* smem,
    const unsigned short* __restrict__ Ap,      // 3 linear planes of x_t
    const unsigned short* __restrict__ Wp,      // 3 linear planes of w1*m1
    const float* __restrict__ bias, float* __restrict__ memOut,
    unsigned char* __restrict__ sbitsOut, int rb, int tid)
{
    auto As = reinterpret_cast<unsigned short(*)[64 * 40]>(smem);              // [3]
    auto Bs = reinterpret_cast<unsigned short(*)[3][64 * 40]>(smem + 15360);   // [2][3]
    const size_t APS = (size_t)BSZ * DIN;
    const size_t BPS = (size_t)HID * DIN;

    const int bn = rb & 31, bm = rb >> 5;
    const int srow = tid >> 2, skq = tid & 3;
    const int lane = tid & 63, wv = tid >> 6;
    const int wm = wv >> 1, wn = wv & 1;
    const int fr = lane & 15, fk = (lane >> 4) * 8;
    const size_t aRow = (size_t)(bm * 64 + srow) * DIN;
    const size_t bRow = (size_t)(bn * 64 + srow) * DIN;
    const int sdst = srow * 40 + skq * 8;

    f32x4 acc[2][2] = {};
    us8 aa0, aa1, aa2, bb0, bb1, bb2;

    auto ldnext = [&](int k0) {
        aa0 = *(const us8*)(Ap + aRow + k0 + skq * 8);
        aa1 = *(const us8*)(Ap + APS + aRow + k0 + skq * 8);
        aa2 = *(const us8*)(Ap + 2 * APS + aRow + k0 + skq * 8);
        bb0 = *(const us8*)(Wp + bRow + k0 + skq * 8);
        bb1 = *(const us8*)(Wp + BPS + bRow + k0 + skq * 8);
        bb2 = *(const us8*)(Wp + 2 * BPS + bRow + k0 + skq * 8);
    };
    auto stageA = [&]() {
        *(us8*)&As[0][sdst] = aa0;
        *(us8*)&As[1][sdst] = aa1;
        *(us8*)&As[2][sdst] = aa2;
    };
    auto stageB = [&](int nb) {
        *(us8*)&Bs[nb][0][sdst] = bb0;
        *(us8*)&Bs[nb][1][sdst] = bb1;
        *(us8*)&Bs[nb][2][sdst] = bb2;
    };

    ldnext(0); stageA(); stageB(0);
    __syncthreads();

    const int nsteps = DIN / 32;      // 32
    for (int s = 0; s < nsteps; s++) {
        const bool more = (s + 1 < nsteps);
        if (more) ldnext((s + 1) * 32);

        bf16x8 af[3][2], bf[3][2];
#pragma unroll
        for (int p = 0; p < 3; p++)
#pragma unroll
            for (int f = 0; f < 2; f++) {
                af[p][f] = *(const bf16x8*)&As[p][(wm * 32 + f * 16 + fr) * 40 + fk];
                bf[p][f] = *(const bf16x8*)&Bs[s & 1][p][(wn * 32 + f * 16 + fr) * 40 + fk];
            }
#pragma unroll
        for (int pa = 0; pa < 3; pa++)
#pragma unroll
            for (int pb = 0; pb < 3; pb++) {
                if (pa + pb <= 2) {
#pragma unroll
                    for (int fm = 0; fm < 2; fm++)
#pragma unroll
                        for (int fn = 0; fn < 2; fn++)
                            acc[fm][fn] = __builtin_amdgcn_mfma_f32_16x16x32_bf16(
                                af[pa][fm], bf[pb][fn], acc[fm][fn], 0, 0, 0);
                }
            }

        __syncthreads();
        if (more) { stageA(); stageB((s + 1) & 1); }
        __syncthreads();
    }

    lif_epi(acc, bias, memOut, sbitsOut, bm, bn, wm, wn, lane);
}

__global__ __launch_bounds__(256)
void snn_step2(const float* __restrict__ x,
               unsigned short* __restrict__ xp,
               const unsigned short* __restrict__ w1p, const float* __restrict__ b1,
               const unsigned short* __restrict__ w2p, const float* __restrict__ b2,
               const unsigned short* __restrict__ w3p, const float* __restrict__ b3,
               const float* __restrict__ wo, const float* __restrict__ bo,
               float* __restrict__ mem1, float* __restrict__ mem2, float* __restrict__ mem3,
               float* __restrict__ memo,
               unsigned char* __restrict__ spk1, unsigned char* __restrict__ spk2,
               unsigned char* __restrict__ spk3,
               float* __restrict__ ssum, int j)
{
    __shared__ __align__(16) unsigned char smem[46080];
    const int bid = blockIdx.x, tid = threadIdx.x;
    const size_t XSLOT = (size_t)3 * BSZ * DIN;

    if (bid < 256) {
        const int t = j;
        if (t <= TSTEPS - 1)
            role_l1p(smem, xp + (size_t)(t & 1) * XSLOT, w1p, b1, mem1,
                     spk1 + (size_t)(t & 1) * SPKB, bid, tid);
    } else if (bid < 512) {
        const int t = j - 1;
        if (t >= 0 && t <= TSTEPS - 1)
            role_l23b(smem, spk1 + (size_t)(t & 1) * SPKB, w2p, b2, mem2,
                      spk2 + (size_t)(t & 1) * SPKB, bid - 256, tid);
    } else if (bid < 768) {
        const int t = j - 2;
        if (t >= 0 && t <= TSTEPS - 1)
            role_l23b(smem, spk2 + (size_t)(t & 1) * SPKB, w3p, b3, mem3,
                      spk3 + (size_t)(t & 1) * SPKB, bid - 512, tid);
    } else {
        const int t1 = j + 1;
        if (t1 <= TSTEPS - 1)
            xsplit_dev(x + (size_t)t1 * BSZ * DIN,
                       xp + (size_t)(t1 & 1) * XSLOT, bid - 768, 128, tid);
        const int t = j - 3;
        if (t >= 0 && t <= TSTEPS - 1) {
            const int lane = tid & 63, wvi = tid >> 6;
            role_out_b(spk3 + (size_t)(t & 1) * SPKB, wo, bo, memo, ssum,
                       (bid - 768) * 4 + wvi, lane);
        }
    }
}

// ===========================================================================
// ===========================  V4 ROLE CODE  ================================
// ===========================================================================

// Layers 2/3 v4: wave tile 64x16 (fm=4, wave wv owns 16 cols). NO barriers,
// no LDS staging. B = 3 fragment-major swizzled planes, one coalesced 1KB
// us8 load per fragment, 2-set static prefetch. A = spike bitmap, 16B per
// 4 steps, expanded via 16-entry nibble LUT in LDS (2x ds_read_b64/frag).
__device__ __forceinline__ void role_l23e(unsigned char* smem,
    const unsigned char* __restrict__ sbitsIn,
    const unsigned short* __restrict__ Bq,      // 3 swizzled planes, stride HID*HID
    const float* __restrict__ bias, float* __restrict__ memOut,
    unsigned char* __restrict__ sbitsOut, int rb, int tid)
{
    u32x2* lut = (u32x2*)smem;                  // 16 x 8 B
    if (tid < 16) {
        u32x2 e;
        e.x = ((tid & 1) ? 0x3F80u : 0u) | ((tid & 2) ? 0x3F800000u : 0u);
        e.y = ((tid & 4) ? 0x3F80u : 0u) | ((tid & 8) ? 0x3F800000u : 0u);
        lut[tid] = e;
    }
    __syncthreads();

    const int bn = rb & 31, bm = rb >> 5;
    const int lane = tid & 63, wv = tid >> 6;
    const int fr = lane & 15, fk = (lane >> 4) * 8;

    const size_t PSQ = (size_t)HID * HID / 8;   // plane stride (us8 units)
    const us8* bP0 = (const us8*)Bq + (size_t)(bn * 4 + wv) * (HID / 32) * 64 + lane;
    const us8* bP1 = bP0 + PSQ;
    const us8* bP2 = bP1 + PSQ;

    const unsigned char* aR = sbitsIn + (size_t)(bm * 64 + fr) * (HID / 8);

    f32x4 acc[4] = {};
    us8 bb[2][3];
    us4 awq[2][4];

#define LDB4(SET, S) do { const int sc_ = (S) < 64 ? (S) : 63;                 \
        bb[SET][0] = bP0[sc_ * 64];                                            \
        bb[SET][1] = bP1[sc_ * 64];                                            \
        bb[SET][2] = bP2[sc_ * 64]; } while (0)

#define LDA4(SET, G) do { const int gc_ = (G) < 16 ? (G) : 15;                 \
        awq[SET][0] = *(const us4*)(aR + 0 * 16 * (HID / 8) + gc_ * 16);       \
        awq[SET][1] = *(const us4*)(aR + 1 * 16 * (HID / 8) + gc_ * 16);       \
        awq[SET][2] = *(const us4*)(aR + 2 * 16 * (HID / 8) + gc_ * 16);       \
        awq[SET][3] = *(const us4*)(aR + 3 * 16 * (HID / 8) + gc_ * 16); } while (0)

#define EXPAND(AF, W) do { unsigned by_ = ((W) >> fk) & 0xFFu;                 \
        u32x2 lo_ = lut[by_ & 15u];                                            \
        u32x2 hi_ = lut[by_ >> 4];                                             \
        ((u32x2*)&(AF))[0] = lo_;                                              \
        ((u32x2*)&(AF))[1] = hi_; } while (0)

#define STEP(BSET, ASET, COMP) do {                                            \
        us8 a0_, a1_, a2_, a3_;                                                \
        EXPAND(a0_, awq[ASET][0][COMP]);                                       \
        EXPAND(a1_, awq[ASET][1][COMP]);                                       \
        EXPAND(a2_, awq[ASET][2][COMP]);                                       \
        EXPAND(a3_, awq[ASET][3][COMP]);                                       \
        bf16x8 b0_ = *(const bf16x8*)&bb[BSET][0];                             \
        bf16x8 b1_ = *(const bf16x8*)&bb[BSET][1];                             \
        bf16x8 b2_ = *(const bf16x8*)&bb[BSET][2];                             \
        bf16x8 fa0_ = *(const bf16x8*)&a0_;                                    \
        bf16x8 fa1_ = *(const bf16x8*)&a1_;                                    \
        bf16x8 fa2_ = *(const bf16x8*)&a2_;                                    \
        bf16x8 fa3_ = *(const bf16x8*)&a3_;                                    \
        acc[0] = __builtin_amdgcn_mfma_f32_16x16x32_bf16(fa0_, b0_, acc[0], 0, 0, 0); \
        acc[0] = __builtin_amdgcn_mfma_f32_16x16x32_bf16(fa0_, b1_, acc[0], 0, 0, 0); \
        acc[0] = __builtin_amdgcn_mfma_f32_16x16x32_bf16(fa0_, b2_, acc[0], 0, 0, 0); \
        acc[1] = __builtin_amdgcn_mfma_f32_16x16x32_bf16(fa1_, b0_, acc[1], 0, 0, 0); \
        acc[1] = __builtin_amdgcn_mfma_f32_16x16x32_bf16(fa1_, b1_, acc[1], 0, 0, 0); \
        acc[1] = __builtin_amdgcn_mfma_f32_16x16x32_bf16(fa1_, b2_, acc[1], 0, 0, 0); \
        acc[2] = __builtin_amdgcn_mfma_f32_16x16x32_bf16(fa2_, b0_, acc[2], 0, 0, 0); \
        acc[2] = __builtin_amdgcn_mfma_f32_16x16x32_bf16(fa2_, b1_, acc[2], 0, 0, 0); \
        acc[2] = __builtin_amdgcn_mfma_f32_16x16x32_bf16(fa2_, b2_, acc[2], 0, 0, 0); \
        acc[3] = __builtin_amdgcn_mfma_f32_16x16x32_bf16(fa3_, b0_, acc[3], 0, 0, 0); \
        acc[3] = __builtin_amdgcn_mfma_f32_16x16x32_bf16(fa3_, b1_, acc[3], 0, 0, 0); \
        acc[3] = __builtin_amdgcn_mfma_f32_16x16x32_bf16(fa3_, b2_, acc[3], 0, 0, 0); \
    } while (0)

    LDB4(0, 0); LDB4(1, 1);
    LDA4(0, 0); LDA4(1, 1);

    for (int g = 0; g < 16; g += 2) {
        const int s0 = g * 4;
        // group g: A set 0
        STEP(0, 0, 0); LDB4(0, s0 + 2);
        STEP(1, 0, 1); LDB4(1, s0 + 3);
        STEP(0, 0, 2); LDB4(0, s0 + 4);
        STEP(1, 0, 3); LDB4(1, s0 + 5);
        LDA4(0, g + 2);
        // group g+1: A set 1
        STEP(0, 1, 0); LDB4(0, s0 + 6);
        STEP(1, 1, 1); LDB4(1, s0 + 7);
        STEP(0, 1, 2); LDB4(0, s0 + 8);
        STEP(1, 1, 3); LDB4(1, s0 + 9);
        LDA4(1, g + 3);
    }

#undef LDB4
#undef LDA4
#undef EXPAND
#undef STEP

    lif_epi4b(acc, bias, memOut, sbitsOut, bm, bn, wv, lane);
}

// Layer 1 v4: LDS single-buffered As[3]+Bs[3] (30720 B), linear xp/w1p planes,
// bitmap spike output. Same MFMA combo order as v2 (bit-identical).
__device__ __forceinline__ void role_l1s(unsigned char* smem,
    const unsigned short* __restrict__ Ap,
    const unsigned short* __restrict__ Wp,
    const float* __restrict__ bias, float* __restrict__ memOut,
    unsigned char* __restrict__ sbitsOut, int rb, int tid)
{
    auto As = reinterpret_cast<unsigned short(*)[64 * 40]>(smem);              // [3]
    auto Bs = reinterpret_cast<unsigned short(*)[64 * 40]>(smem + 15360);      // [3]
    const size_t APS = (size_t)BSZ * DIN;
    const size_t BPS = (size_t)HID * DIN;

    const int bn = rb & 31, bm = rb >> 5;
    const int srow = tid >> 2, skq = tid & 3;
    const int lane = tid & 63, wv = tid >> 6;
    const int wm = wv >> 1, wn = wv & 1;
    const int fr = lane & 15, fk = (lane >> 4) * 8;
    const size_t aRow = (size_t)(bm * 64 + srow) * DIN;
    const size_t bRow = (size_t)(bn * 64 + srow) * DIN;
    const int sdst = srow * 40 + skq * 8;

    f32x4 acc[2][2] = {};
    us8 aa0, aa1, aa2, bb0, bb1, bb2;

    auto ldnext = [&](int k0) {
        aa0 = *(const us8*)(Ap + aRow + k0 + skq * 8);
        aa1 = *(const us8*)(Ap + APS + aRow + k0 + skq * 8);
        aa2 = *(const us8*)(Ap + 2 * APS + aRow + k0 + skq * 8);
        bb0 = *(const us8*)(Wp + bRow + k0 + skq * 8);
        bb1 = *(const us8*)(Wp + BPS + bRow + k0 + skq * 8);
        bb2 = *(const us8*)(Wp + 2 * BPS + bRow + k0 + skq * 8);
    };
    auto stageAB = [&]() {
        *(us8*)&As[0][sdst] = aa0;
        *(us8*)&As[1][sdst] = aa1;
        *(us8*)&As[2][sdst] = aa2;
        *(us8*)&Bs[0][sdst] = bb0;
        *(us8*)&Bs[1][sdst] = bb1;
        *(us8*)&Bs[2][sdst] = bb2;
    };

    ldnext(0); stageAB();
    __syncthreads();

    const int nsteps = DIN / 32;      // 32
    for (int s = 0; s < nsteps; s++) {
        const bool more = (s + 1 < nsteps);
        if (more) ldnext((s + 1) * 32);

        bf16x8 af[3][2], bf[3][2];
#pragma unroll
        for (int p = 0; p < 3; p++)
#pragma unroll
            for (int f = 0; f < 2; f++) {
                af[p][f] = *(const bf16x8*)&As[p][(wm * 32 + f * 16 + fr) * 40 + fk];
                bf[p][f] = *(const bf16x8*)&Bs[p][(wn * 32 + f * 16 + fr) * 40 + fk];
            }
#pragma unroll
        for (int pa = 0; pa < 3; pa++)
#pragma unroll
            for (int pb = 0; pb < 3; pb++) {
                if (pa + pb <= 2) {
#pragma unroll
                    for (int fm = 0; fm < 2; fm++)
#pragma unroll
                        for (int fn = 0; fn < 2; fn++)
                            acc[fm][fn] = __builtin_amdgcn_mfma_f32_16x16x32_bf16(
                                af[pa][fm], bf[pb][fn], acc[fm][fn], 0, 0, 0);
                }
            }

        __syncthreads();                       // readers done
        if (more) stageAB();
        __syncthreads();                       // writers done
    }

    lif_epi(acc, bias, memOut, sbitsOut, bm, bn, wm, wn, lane);
}

// ---------------------------------------------------------------------------
// V4 fused pipeline step (diagonal j), grid 1024 = exactly 4 blocks/CU:
//   L1(t=j) | L2(t=j-1) | L3(t=j-2) | XS(t=j+1)+OUT(t=j-3)
// ---------------------------------------------------------------------------
__global__ __launch_bounds__(256, 4)
void snn_step4(const float* __restrict__ x,
               unsigned short* __restrict__ xp,
               const unsigned short* __restrict__ w1p, const float* __restrict__ b1,
               const unsigned short* __restrict__ w2q, const float* __restrict__ b2,
               const unsigned short* __restrict__ w3q, const float* __restrict__ b3,
               const float* __restrict__ wo, const float* __restrict__ bo,
               float* __restrict__ mem1, float* __restrict__ mem2, float* __restrict__ mem3,
               float* __restrict__ memo,
               unsigned char* __restrict__ spk1, unsigned char* __restrict__ spk2,
               unsigned char* __restrict__ spk3,
               float* __restrict__ ssum, int j)
{
    __shared__ __align__(16) unsigned char smem[30720];
    const int bid = blockIdx.x, tid = threadIdx.x;
    const size_t XSLOT = (size_t)3 * BSZ * DIN;

    if (bid < 256) {
        const int t = j;
        if (t <= TSTEPS - 1)
            role_l1s(smem, xp + (size_t)(t & 1) * XSLOT, w1p, b1, mem1,
                     spk1 + (size_t)(t & 1) * SPKB, bid, tid);
    } else if (bid < 512) {
        const int t = j - 1;
        if (t >= 0 && t <= TSTEPS - 1)
            role_l23e(smem, spk1 + (size_t)(t & 1) * SPKB, w2q, b2, mem2,
                      spk2 + (size_t)(t & 1) * SPKB, bid - 256, tid);
    } else if (bid < 768) {
        const int t = j - 2;
        if (t >= 0 && t <= TSTEPS - 1)
            role_l23e(smem, spk2 + (size_t)(t & 1) * SPKB, w3q, b3, mem3,
                      spk3 + (size_t)(t & 1) * SPKB, bid - 512, tid);
    } else {
        const int t1 = j + 1;
        if (t1 <= TSTEPS - 1)
            xsplit_dev(x + (size_t)t1 * BSZ * DIN,
                       xp + (size_t)(t1 & 1) * XSLOT, bid - 768, 256, tid);
        const int t = j - 3;
        if (t >= 0 && t <= TSTEPS - 1) {
            const int lane = tid & 63, wvi = tid >> 6;
            if (wvi < 2)
                role_out_b(spk3 + (size_t)(t & 1) * SPKB, wo, bo, memo, ssum,
                           (bid - 768) * 2 + wvi, lane);
        }
    }
}

// ---------------------------------------------------------------------------
extern "C" void kernel_launch(void* const* d_in, const int* in_sizes, int n_in,
                              void* d_out, int out_size, void* d_ws, size_t ws_size,
                              hipStream_t stream)
{
    const float* x  = (const float*)d_in[0];
    const float* w1 = (const float*)d_in[1];
    const float* b1 = (const float*)d_in[2];
    const float* m1 = (const float*)d_in[3];
    const float* w2 = (const float*)d_in[4];
    const float* b2 = (const float*)d_in[5];
    const float* m2 = (const float*)d_in[6];
    const float* w3 = (const float*)d_in[7];
    const float* b3 = (const float*)d_in[8];
    const float* m3 = (const float*)d_in[9];
    const float* wo = (const float*)d_in[10];
    const float* bo = (const float*)d_in[11];
    float* out = (float*)d_out;

    const size_t planeB  = (size_t)HID * HID * 2;   // 8,388,608
    const size_t plane1B = (size_t)HID * DIN * 2;   // 4,194,304
    const size_t planeXB = (size_t)BSZ * DIN * 2;   // 1,048,576
    const size_t memB    = (size_t)BSZ * HID * 4;   // 4,194,304
    const size_t memoB   = (size_t)BSZ * NCLS * 4;  // 20,480
    const size_t spk2B   = 2 * SPKB;                // 262,144

    unsigned char* base = (unsigned char*)d_ws;

    const size_t needV4 = 6 * planeB + 3 * plane1B + 6 * planeXB
                        + 3 * memB + memoB + 3 * spk2B + 4096;   // 82,599,936

    const int nW1  = HID * DIN / 4;
    const size_t HH = (size_t)HID * HID;
    const size_t HD = (size_t)HID * DIN;

    if (ws_size >= needV4) {
        // ---------------- V4 path ----------------
        unsigned short* w2q = (unsigned short*)base;
        unsigned short* w3q = (unsigned short*)(base + 3 * planeB);
        unsigned short* w1p = (unsigned short*)(base + 6 * planeB);
        unsigned short* xp  = (unsigned short*)(base + 6 * planeB + 3 * plane1B);
        unsigned char* mbase = base + 6 * planeB + 3 * plane1B + 6 * planeXB;
        float* mem1 = (float*)(mbase);
        float* mem2 = (float*)(mbase + memB);
        float* mem3 = (float*)(mbase + 2 * memB);
        float* memo = (float*)(mbase + 3 * memB);
        unsigned char* spk1 = mbase + 3 * memB + memoB;
        unsigned char* spk2 = spk1 + spk2B;
        unsigned char* spk3 = spk2 + spk2B;

        split3q<<<2048, 256, 0, stream>>>(w2, m2, w2q);
        split3q<<<2048, 256, 0, stream>>>(w3, m3, w3q);
        split3<<<1024, 256, 0, stream>>>(w1, m1, w1p, w1p + HD, w1p + 2 * HD, nW1);
        xsplit_k<<<256, 256, 0, stream>>>(x, xp);   // t=0 into slot 0

        zerof<<<1024, 256, 0, stream>>>(mem1, (int)((3 * memB + memoB) / 16));
        zerof<<<8, 256, 0, stream>>>(out, (BSZ * NCLS) / 4);

        for (int j = 0; j <= TSTEPS + 2; j++) {   // 35 diagonals
            snn_step4<<<1024, 256, 0, stream>>>(x, xp, w1p, b1, w2q, b2, w3q, b3,
                                                wo, bo, mem1, mem2, mem3, memo,
                                                spk1, spk2, spk3, out, j);
        }
        return;
    }

    // ---------------- V2 fallback (verified 2407 us) ----------------
    const size_t needV2 = 6 * planeB + 3 * plane1B + 6 * planeXB
                        + 3 * memB + memoB + 3 * spk2B;          // 82,595,840
    if (ws_size < needV2) return;   // cannot run safely (never happens on this harness)

    unsigned short* w2p = (unsigned short*)base;
    unsigned short* w3p = (unsigned short*)(base + 3 * planeB);
    unsigned short* w1p = (unsigned short*)(base + 6 * planeB);
    unsigned short* xp  = (unsigned short*)(base + 6 * planeB + 3 * plane1B);
    unsigned char* mbase = base + 6 * planeB + 3 * plane1B + 6 * planeXB;
    float* mem1 = (float*)(mbase);
    float* mem2 = (float*)(mbase + memB);
    float* mem3 = (float*)(mbase + 2 * memB);
    float* memo = (float*)(mbase + 3 * memB);
    unsigned char* spk1 = mbase + 3 * memB + memoB;
    unsigned char* spk2 = spk1 + spk2B;
    unsigned char* spk3 = spk2 + spk2B;

    const int nW23 = HID * HID / 4;
    split3<<<1024, 256, 0, stream>>>(w2, m2, w2p, w2p + HH, w2p + 2 * HH, nW23);
    split3<<<1024, 256, 0, stream>>>(w3, m3, w3p, w3p + HH, w3p + 2 * HH, nW23);
    split3<<<1024, 256, 0, stream>>>(w1, m1, w1p, w1p + HD, w1p + 2 * HD, nW1);
    xsplit_k<<<256, 256, 0, stream>>>(x, xp);

    zerof<<<1024, 256, 0, stream>>>(mem1, (int)((3 * memB + memoB) / 16));
    zerof<<<8, 256, 0, stream>>>(out, (BSZ * NCLS) / 4);

    for (int j = 0; j <= TSTEPS + 2; j++) {
        snn_step2<<<896, 256, 0, stream>>>(x, xp, w1p, b1, w2p, b2, w3p, b3,
                                           wo, bo, mem1, mem2, mem3, memo,
                                           spk1, spk2, spk3, out, j);
    }
}